// Round 15
// baseline (917.142 us; speedup 1.0000x reference)
//
#include <hip/hip_runtime.h>
#include <math.h>

#define D_DIM    2048
#define BT_DIM   16384   // B*T
#define NSLOTS   4096
#define SCALE    0.02209708691207961f  // 1/sqrt(2048)
#define MARGIN   0.02f
#define CAND_MAX 16
#define MSCALE   4096.0f
#define MUNSCALE 0.000244140625f   // 1/4096

typedef __attribute__((ext_vector_type(8))) short bf16x8;
typedef __attribute__((ext_vector_type(8))) _Float16 f16x8;
typedef __attribute__((ext_vector_type(4))) float f32x4;
typedef __attribute__((ext_vector_type(8))) unsigned short u16x8;
typedef __attribute__((ext_vector_type(4))) unsigned short u16x4;

__device__ __forceinline__ unsigned short f2bf(float f) {
    unsigned int u = __float_as_uint(f);
    return (unsigned short)((u + 0x7fffu + ((u >> 16) & 1u)) >> 16);
}
__device__ __forceinline__ float bf2f(unsigned short s) {
    return __uint_as_float(((unsigned int)s) << 16);
}

__device__ __forceinline__ void async_cp16(const void* g, void* l) {
    __builtin_amdgcn_global_load_lds(
        (const __attribute__((address_space(1))) void*)g,
        (__attribute__((address_space(3))) void*)l, 16, 0, 0);
}

// ---------------------------------------------------------------------------
// top-4 helpers (jax semantics: val desc, idx asc) -- used in exact re-score
// ---------------------------------------------------------------------------
__device__ __forceinline__ bool cand_better(float v, int i, float v2, int i2) {
    return (v > v2) || (v == v2 && i < i2);
}

__device__ __forceinline__ void cand_insert(float v, int idx,
                                            float& v0, int& i0, float& v1, int& i1,
                                            float& v2, int& i2, float& v3, int& i3) {
    if (cand_better(v, idx, v3, i3)) {
        if (cand_better(v, idx, v0, i0)) {
            v3 = v2; i3 = i2; v2 = v1; i2 = i1; v1 = v0; i1 = i0; v0 = v; i0 = idx;
        } else if (cand_better(v, idx, v1, i1)) {
            v3 = v2; i3 = i2; v2 = v1; i2 = i1; v1 = v; i1 = idx;
        } else if (cand_better(v, idx, v2, i2)) {
            v3 = v2; i3 = i2; v2 = v; i2 = idx;
        } else {
            v3 = v; i3 = idx;
        }
    }
}

// ---------------------------------------------------------------------------
// f16 2-way split with scaled residual (r15): v = h + m/4096,
// h = f16(v) (rel 2^-11), m = f16(4096*(v-h)) -- residual scaled into f16
// NORMAL range (avoids subnormal/FTZ risk). Combined rep err ~1.2*2^-22|v|.
// ---------------------------------------------------------------------------
__device__ __forceinline__ void split2v(float v, unsigned short& hb,
                                        unsigned short& mb) {
    _Float16 h = (_Float16)v;
    const float r = v - (float)h;
    _Float16 m = (_Float16)(r * MSCALE);
    __builtin_memcpy(&hb, &h, 2);
    __builtin_memcpy(&mb, &m, 2);
}

// SK -> 2 f16 component arrays (linear, 4 elems/thread)
__global__ __launch_bounds__(256)
void split2_lin(const float* __restrict__ in, unsigned short* __restrict__ oh,
                unsigned short* __restrict__ om) {
    const size_t i = ((size_t)blockIdx.x * 256 + threadIdx.x) * 4;
    const float4 v = *(const float4*)(in + i);
    u16x4 h, m;
    unsigned short th, tm;
    split2v(v.x, th, tm); h[0] = th; m[0] = tm;
    split2v(v.y, th, tm); h[1] = th; m[1] = tm;
    split2v(v.z, th, tm); h[2] = th; m[2] = tm;
    split2v(v.w, th, tm); h[3] = th; m[3] = tm;
    *(u16x4*)(oh + i) = h;
    *(u16x4*)(om + i) = m;
}

// Wq[e][d] -> transposed 2 f16 component arrays out[d][e]  (32x32 LDS tiles)
__global__ __launch_bounds__(256)
void split2_wqT(const float* __restrict__ W, unsigned short* __restrict__ th,
                unsigned short* __restrict__ tm) {
    __shared__ float tile[32][33];
    const int tx  = threadIdx.x & 31;
    const int ty4 = (threadIdx.x >> 5) * 4;
    const int e0  = blockIdx.y * 32;
    const int d0  = blockIdx.x * 32;
#pragma unroll
    for (int r = 0; r < 4; ++r)
        tile[ty4 + r][tx] = W[(size_t)(e0 + ty4 + r) * D_DIM + (d0 + tx)];
    __syncthreads();
#pragma unroll
    for (int r = 0; r < 4; ++r) {
        const float v = tile[tx][ty4 + r];   // = W[e0+tx][d0+ty4+r]
        unsigned short h, m;
        split2v(v, h, m);
        const size_t o = (size_t)(d0 + ty4 + r) * D_DIM + (e0 + tx);
        th[o] = h; tm[o] = m;
    }
}

// ---------------------------------------------------------------------------
// fp32 -> bf16 elementwise (8 elems/thread), exact grid
// ---------------------------------------------------------------------------
__global__ __launch_bounds__(256)
void cvt_f32_bf16(const float* __restrict__ in, unsigned short* __restrict__ out) {
    const size_t i = ((size_t)blockIdx.x * 256 + threadIdx.x) * 8;
    float4 a = *(const float4*)(in + i);
    float4 b = *(const float4*)(in + i + 4);
    u16x8 o;
    o[0] = f2bf(a.x); o[1] = f2bf(a.y); o[2] = f2bf(a.z); o[3] = f2bf(a.w);
    o[4] = f2bf(b.x); o[5] = f2bf(b.y); o[6] = f2bf(b.z); o[7] = f2bf(b.w);
    *(u16x8*)(out + i) = o;
}

// ---------------------------------------------------------------------------
// KW = SK @ Wq via 3-product f16-split MFMA (fp32-grade), r15:
//   acc1 = sum Ah*Bh ; acc2 = sum (Am*Bh + Ah*Bm)   [m pre-scaled by 4096]
//   KW = acc1 + acc2/4096
// Dropped mm'/4096^2 term ~2^-22 rel/elem -> KW-elem err ~1e-9 (same grade
// as r12's validated 6-product bf16 path). Half the MFMA, 2/3 the staging.
// ---------------------------------------------------------------------------
__global__ __launch_bounds__(256)
void gemm_kw_f16(const unsigned short* __restrict__ Ah,
                 const unsigned short* __restrict__ Am,
                 const unsigned short* __restrict__ Bh,
                 const unsigned short* __restrict__ Bm,
                 float* __restrict__ KW, unsigned short* __restrict__ kwb,
                 int M, int N, int K) {
    __shared__ __align__(16) unsigned short AldsH[128 * 32];
    __shared__ __align__(16) unsigned short AldsM[128 * 32];
    __shared__ __align__(16) unsigned short BldsH[128 * 32];
    __shared__ __align__(16) unsigned short BldsM[128 * 32];

    const int tid  = threadIdx.x;
    const int lane = tid & 63;
    const int w    = tid >> 6;
    const int wr   = w >> 1, wc = w & 1;
    const int bmr  = blockIdx.y * 128;
    const int bnc  = blockIdx.x * 128;

    const int srow = lane >> 2;
    const int skch = (lane & 3) ^ ((lane >> 3) & 3);
    const int c0 = w, c1 = w + 4;
    size_t oA0 = (size_t)(bmr + c0 * 16 + srow) * K + skch * 8;
    size_t oA1 = (size_t)(bmr + c1 * 16 + srow) * K + skch * 8;
    size_t oB0 = (size_t)(bnc + c0 * 16 + srow) * K + skch * 8;
    size_t oB1 = (size_t)(bnc + c1 * 16 + srow) * K + skch * 8;
    char* lAh0 = (char*)AldsH + c0 * 1024;  char* lAh1 = (char*)AldsH + c1 * 1024;
    char* lAm0 = (char*)AldsM + c0 * 1024;  char* lAm1 = (char*)AldsM + c1 * 1024;
    char* lBh0 = (char*)BldsH + c0 * 1024;  char* lBh1 = (char*)BldsH + c1 * 1024;
    char* lBm0 = (char*)BldsM + c0 * 1024;  char* lBm1 = (char*)BldsM + c1 * 1024;

    const int kbyte = (((lane >> 4) ^ ((lane >> 1) & 3)) << 4);
    const int rA = wr * 64 + (lane & 15);
    const int rB = wc * 64 + (lane & 15);

    f32x4 acc1[4][4] = {};
    f32x4 acc2[4][4] = {};

    for (int kt = 0; kt < K; kt += 32) {
        async_cp16(Ah + oA0, lAh0);  async_cp16(Ah + oA1, lAh1);
        async_cp16(Am + oA0, lAm0);  async_cp16(Am + oA1, lAm1);
        async_cp16(Bh + oB0, lBh0);  async_cp16(Bh + oB1, lBh1);
        async_cp16(Bm + oB0, lBm0);  async_cp16(Bm + oB1, lBm1);
        oA0 += 32; oA1 += 32; oB0 += 32; oB1 += 32;
        __syncthreads();

        f16x8 afh[4], afm[4], bfh[4], bfm[4];
#pragma unroll
        for (int i = 0; i < 4; ++i) {
            const int ar = (rA + i * 16) * 64 + kbyte;
            afh[i] = *(const f16x8*)((const char*)AldsH + ar);
            afm[i] = *(const f16x8*)((const char*)AldsM + ar);
            const int br = (rB + i * 16) * 64 + kbyte;
            bfh[i] = *(const f16x8*)((const char*)BldsH + br);
            bfm[i] = *(const f16x8*)((const char*)BldsM + br);
        }
#pragma unroll
        for (int i = 0; i < 4; ++i)
#pragma unroll
            for (int j = 0; j < 4; ++j) {
                acc1[i][j] = __builtin_amdgcn_mfma_f32_16x16x32_f16(
                    afh[i], bfh[j], acc1[i][j], 0, 0, 0);
                f32x4 c2 = acc2[i][j];
                c2 = __builtin_amdgcn_mfma_f32_16x16x32_f16(afm[i], bfh[j], c2, 0, 0, 0);
                c2 = __builtin_amdgcn_mfma_f32_16x16x32_f16(afh[i], bfm[j], c2, 0, 0, 0);
                acc2[i][j] = c2;
            }
        __syncthreads();
    }

    const int orow = (lane >> 4) * 4;
    const int ocol = lane & 15;
#pragma unroll
    for (int i = 0; i < 4; ++i)
#pragma unroll
        for (int j = 0; j < 4; ++j) {
            const size_t base =
                (size_t)(bmr + wr * 64 + i * 16 + orow) * N + (bnc + wc * 64 + j * 16 + ocol);
#pragma unroll
            for (int r = 0; r < 4; ++r) {
                const float v = acc1[i][j][r] + acc2[i][j][r] * MUNSCALE;
                KW[base + (size_t)r * N]  = v;
                kwb[base + (size_t)r * N] = f2bf(v);
            }
        }
}

// ---------------------------------------------------------------------------
// bf16 MFMA GEMM: C[M,N] = A[M,K] @ B[N,K]^T; C fp32 or bf16 (template).
// r7 exact baseline (no swizzle, no epilogue fusion -- r8/r10 lessons).
// Used for: scores (bf16 out), SVW = SV @ Wout^T (fp32 out).
// ---------------------------------------------------------------------------
template <bool BF16_OUT>
__global__ __launch_bounds__(256)
void gemm_bf16_abt(const unsigned short* __restrict__ A,
                   const unsigned short* __restrict__ B,
                   void* __restrict__ Cv, int M, int N, int K) {
    __shared__ __align__(16) unsigned short Alds[128 * 32];
    __shared__ __align__(16) unsigned short Blds[128 * 32];

    const int tid  = threadIdx.x;
    const int lane = tid & 63;
    const int w    = tid >> 6;
    const int wr   = w >> 1, wc = w & 1;
    const int bm   = blockIdx.y * 128;
    const int bn   = blockIdx.x * 128;

    const int srow = lane >> 2;
    const int skch = (lane & 3) ^ ((lane >> 3) & 3);
    const int c0 = w, c1 = w + 4;
    const unsigned short* gA0 = A + (size_t)(bm + c0 * 16 + srow) * K + skch * 8;
    const unsigned short* gA1 = A + (size_t)(bm + c1 * 16 + srow) * K + skch * 8;
    const unsigned short* gB0 = B + (size_t)(bn + c0 * 16 + srow) * K + skch * 8;
    const unsigned short* gB1 = B + (size_t)(bn + c1 * 16 + srow) * K + skch * 8;
    char* lA0 = (char*)Alds + c0 * 1024;
    char* lA1 = (char*)Alds + c1 * 1024;
    char* lB0 = (char*)Blds + c0 * 1024;
    char* lB1 = (char*)Blds + c1 * 1024;

    const int kbyte = (((lane >> 4) ^ ((lane >> 1) & 3)) << 4);
    const int rA = wr * 64 + (lane & 15);
    const int rB = wc * 64 + (lane & 15);

    f32x4 acc[4][4] = {};

    for (int kt = 0; kt < K; kt += 32) {
        async_cp16(gA0, lA0);
        async_cp16(gA1, lA1);
        async_cp16(gB0, lB0);
        async_cp16(gB1, lB1);
        gA0 += 32; gA1 += 32; gB0 += 32; gB1 += 32;
        __syncthreads();

        bf16x8 a[4], b[4];
#pragma unroll
        for (int i = 0; i < 4; ++i) {
            a[i] = *(const bf16x8*)((const char*)Alds + (rA + i * 16) * 64 + kbyte);
            b[i] = *(const bf16x8*)((const char*)Blds + (rB + i * 16) * 64 + kbyte);
        }
#pragma unroll
        for (int i = 0; i < 4; ++i)
#pragma unroll
            for (int j = 0; j < 4; ++j)
                acc[i][j] = __builtin_amdgcn_mfma_f32_16x16x32_bf16(
                    a[i], b[j], acc[i][j], 0, 0, 0);
        __syncthreads();
    }

    const int orow = (lane >> 4) * 4;
    const int ocol = lane & 15;
#pragma unroll
    for (int i = 0; i < 4; ++i)
#pragma unroll
        for (int j = 0; j < 4; ++j) {
            const size_t base =
                (size_t)(bm + wr * 64 + i * 16 + orow) * N + (bn + wc * 64 + j * 16 + ocol);
#pragma unroll
            for (int r = 0; r < 4; ++r) {
                if constexpr (BF16_OUT)
                    ((unsigned short*)Cv)[base + (size_t)r * N] = f2bf(acc[i][j][r]);
                else
                    ((float*)Cv)[base + (size_t)r * N] = acc[i][j][r];
            }
        }
}

// ---------------------------------------------------------------------------
// Merged refine (r13 validated) + SVW-gather epilogue (r14 validated):
//   branchless in-register row top-4 -> margin candidates -> EXACT fp32
//   re-score (identical math, rounds 2-14) -> softmax ->
//   out_row = sum_k attn_k * SVW[idx_k]   (fp32 gather, writes d_out direct)
// ---------------------------------------------------------------------------
__global__ __launch_bounds__(256)
void topk_refine(const unsigned short* __restrict__ scoresb,
                 const float* __restrict__ x,
                 const float* __restrict__ KW,
                 const float* __restrict__ SVW,
                 float* __restrict__ out) {
    const int tid  = threadIdx.x;
    const int lane = tid & 63;
    const int w    = tid >> 6;
    const int t    = blockIdx.x * 4 + w;
    const unsigned short* srow = scoresb + (size_t)t * NSLOTS;

    __shared__ int cand[4][CAND_MAX];
    __shared__ int ncand[4];

    // ---- load 64 bf16 scores/lane, build order-isomorphic packed keys
    unsigned int k[64];
#pragma unroll
    for (int j = 0; j < 8; ++j) {
        const int c0 = j * 512 + lane * 8;
        const u16x8 s8 = *(const u16x8*)(srow + c0);
#pragma unroll
        for (int e = 0; e < 8; ++e) {
            const unsigned int b   = (unsigned int)s8[e] & 0xffffu;
            const unsigned int ord = b ^ ((b & 0x8000u) ? 0xffffu : 0x8000u);
            k[j * 8 + e] = (ord << 12) | (4095u - (unsigned int)(c0 + e));
        }
    }

    // ---- branchless top-4 over the whole row
    unsigned int win[4];
#pragma unroll
    for (int p = 0; p < 4; ++p) {
        unsigned int a16[16];
#pragma unroll
        for (int e = 0; e < 16; ++e)
            a16[e] = max(max(k[e], k[e + 16]), max(k[e + 32], k[e + 48]));
        unsigned int a4[4];
#pragma unroll
        for (int e = 0; e < 4; ++e)
            a4[e] = max(max(a16[e], a16[e + 4]), max(a16[e + 8], a16[e + 12]));
        unsigned int m = max(max(a4[0], a4[1]), max(a4[2], a4[3]));
#pragma unroll
        for (int off = 1; off < 64; off <<= 1)
            m = max(m, (unsigned int)__shfl_xor((int)m, off));
        win[p] = m;
#pragma unroll
        for (int e = 0; e < 64; ++e) k[e] = (k[e] == m) ? 0u : k[e];
    }

    // decode 4th-best value -> threshold
    const unsigned int ord3 = win[3] >> 12;
    const unsigned int b3 =
        (ord3 & 0x8000u) ? (ord3 ^ 0x8000u) : (~ord3 & 0xffffu);
    const float thresh = bf2f((unsigned short)b3) - MARGIN;

    if (lane == 0) {
        ncand[w] = 4;
        cand[w][0] = 4095 - (int)(win[0] & 0xfffu);
        cand[w][1] = 4095 - (int)(win[1] & 0xfffu);
        cand[w][2] = 4095 - (int)(win[2] & 0xfffu);
        cand[w][3] = 4095 - (int)(win[3] & 0xfffu);
    }
    __syncthreads();

    // ---- margin candidates from remaining keys (masked keys decode NaN)
#pragma unroll
    for (int e = 0; e < 64; ++e) {
        const unsigned int kk  = k[e];
        const unsigned int ordv = kk >> 12;
        const unsigned int bv =
            (ordv & 0x8000u) ? (ordv ^ 0x8000u) : (~ordv & 0xffffu);
        if (bf2f((unsigned short)bv) >= thresh) {
            int p = atomicAdd(&ncand[w], 1);
            if (p < CAND_MAX) cand[w][p] = 4095 - (int)(kk & 0xfffu);
        }
    }
    __syncthreads();
    const int nc = min(ncand[w], CAND_MAX);

    // ---- exact fp32 re-score (IDENTICAL math to rounds 2-14 validated path)
    const float* xrow = x + (size_t)t * D_DIM + lane * 4;
    float4 xv[8];
#pragma unroll
    for (int i = 0; i < 8; ++i) xv[i] = *(const float4*)(xrow + 256 * i);

    float r0 = -INFINITY, r1 = -INFINITY, r2 = -INFINITY, r3 = -INFINITY;
    int   q0 = 0x7fffffff, q1 = 0x7fffffff, q2 = 0x7fffffff, q3 = 0x7fffffff;
    for (int c = 0; c < nc; ++c) {
        const int slot = cand[w][c];
        const float* kr = KW + (size_t)slot * D_DIM + lane * 4;
        float p = 0.0f;
#pragma unroll
        for (int i = 0; i < 8; ++i) {
            const float4 k4 = *(const float4*)(kr + 256 * i);
            p = fmaf(xv[i].x, k4.x, p);
            p = fmaf(xv[i].y, k4.y, p);
            p = fmaf(xv[i].z, k4.z, p);
            p = fmaf(xv[i].w, k4.w, p);
        }
#pragma unroll
        for (int off = 1; off < 64; off <<= 1) p += __shfl_xor(p, off);
        cand_insert(p, slot, r0, q0, r1, q1, r2, q2, r3, q3);
    }

    // ---- softmax over scaled top-4 (r0 is max)
    const float e1s = expf(SCALE * (r1 - r0));
    const float e2s = expf(SCALE * (r2 - r0));
    const float e3s = expf(SCALE * (r3 - r0));
    const float inv = 1.0f / (1.0f + e1s + e2s + e3s);
    const float w0s = inv, w1s = e1s * inv, w2s = e2s * inv, w3s = e3s * inv;

    // ---- gather fp32 SVW rows, weighted sum, write d_out directly
    const float* p0 = SVW + (size_t)q0 * D_DIM;
    const float* p1 = SVW + (size_t)q1 * D_DIM;
    const float* p2 = SVW + (size_t)q2 * D_DIM;
    const float* p3 = SVW + (size_t)q3 * D_DIM;
    float* orow = out + (size_t)t * D_DIM;
#pragma unroll
    for (int i = 0; i < 4; ++i) {
        const int d0 = lane * 8 + 512 * i;
        float4 a0 = *(const float4*)(p0 + d0), b0 = *(const float4*)(p0 + d0 + 4);
        float4 a1 = *(const float4*)(p1 + d0), b1 = *(const float4*)(p1 + d0 + 4);
        float4 a2 = *(const float4*)(p2 + d0), b2 = *(const float4*)(p2 + d0 + 4);
        float4 a3 = *(const float4*)(p3 + d0), b3v = *(const float4*)(p3 + d0 + 4);
        float4 oa, ob;
        oa.x = w0s * a0.x + w1s * a1.x + w2s * a2.x + w3s * a3.x;
        oa.y = w0s * a0.y + w1s * a1.y + w2s * a2.y + w3s * a3.y;
        oa.z = w0s * a0.z + w1s * a1.z + w2s * a2.z + w3s * a3.z;
        oa.w = w0s * a0.w + w1s * a1.w + w2s * a2.w + w3s * a3.w;
        ob.x = w0s * b0.x + w1s * b1.x + w2s * b2.x + w3s * b3v.x;
        ob.y = w0s * b0.y + w1s * b1.y + w2s * b2.y + w3s * b3v.y;
        ob.z = w0s * b0.z + w1s * b1.z + w2s * b2.z + w3s * b3v.z;
        ob.w = w0s * b0.w + w1s * b1.w + w2s * b2.w + w3s * b3v.w;
        *(float4*)(orow + d0)     = oa;
        *(float4*)(orow + d0 + 4) = ob;
    }
}

// ---------------------------------------------------------------------------
extern "C" void kernel_launch(void* const* d_in, const int* in_sizes, int n_in,
                              void* d_out, int out_size, void* d_ws, size_t ws_size,
                              hipStream_t stream) {
    const float* x    = (const float*)d_in[0];
    const float* sk   = (const float*)d_in[1];
    const float* sv   = (const float*)d_in[2];
    const float* wq   = (const float*)d_in[3];
    const float* wout = (const float*)d_in[4];

    // workspace layout (r1 proved ws >= 402.6 MB)
    char* base = (char*)d_ws;
    unsigned short* scoresb = (unsigned short*)base;              // 134.2 MB
    float*          KW      = (float*)(base + 134217728);         //  33.55 MB
    unsigned short* kwb     = (unsigned short*)(base + 167772160);//  16.78 MB
    unsigned short* woutb   = (unsigned short*)(base + 184549376);//   8.39 MB
    unsigned short* xb      = (unsigned short*)(base + 192937984);//  67.11 MB
    unsigned short* svb     = (unsigned short*)(base + 260046848);//  16.78 MB
    unsigned short* skh     = (unsigned short*)(base + 293601280);//  16.78 MB (f16 h; dead after kw)
    unsigned short* skm     = (unsigned short*)(base + 310378496);//  16.78 MB (f16 m; dead after kw)
    unsigned short* wqth    = (unsigned short*)(base + 343932928);//   8.39 MB (f16 h, transposed)
    unsigned short* wqtm    = (unsigned short*)(base + 352321536);//   8.39 MB (f16 m, transposed)
    float*          SVW     = (float*)(base + 293601280);         //  33.55 MB (over skh/skm)

    const dim3 blk(256);

    // f16 2-way splits: SK (linear) and Wq (transposed)
    split2_lin<<<dim3((NSLOTS * (size_t)D_DIM) / 1024), blk, 0, stream>>>(
        sk, skh, skm);
    split2_wqT<<<dim3(D_DIM / 32, D_DIM / 32), blk, 0, stream>>>(
        wq, wqth, wqtm);

    // bf16 copies
    cvt_f32_bf16<<<dim3((BT_DIM * (size_t)D_DIM) / 2048), blk, 0, stream>>>(x, xb);
    cvt_f32_bf16<<<dim3((D_DIM * (size_t)D_DIM) / 2048), blk, 0, stream>>>(wout, woutb);
    cvt_f32_bf16<<<dim3((NSLOTS * (size_t)D_DIM) / 2048), blk, 0, stream>>>(sv, svb);

    // KW (fp32) + kwb (bf16) via 3-product f16-split MFMA
    gemm_kw_f16<<<dim3(D_DIM / 128, NSLOTS / 128), blk, 0, stream>>>(
        skh, skm, wqth, wqtm, KW, kwb, NSLOTS, D_DIM, D_DIM);

    // SVW = SV @ Wout^T (fp32 out) -- launched AFTER kw (overwrites skh/skm)
    gemm_bf16_abt<false><<<dim3(D_DIM / 128, NSLOTS / 128), blk, 0, stream>>>(
        svb, woutb, SVW, NSLOTS, D_DIM, D_DIM);

    // approx scores (bf16 out) = xb @ kwb^T
    gemm_bf16_abt<true><<<dim3(NSLOTS / 128, BT_DIM / 128), blk, 0, stream>>>(
        xb, kwb, scoresb, BT_DIM, NSLOTS, D_DIM);

    // merged top-4 + exact refine + SVW gather -> writes d_out directly
    topk_refine<<<dim3(BT_DIM / 4), blk, 0, stream>>>(
        scoresb, x, KW, SVW, (float*)d_out);
}

// Round 16
// 895.632 us; speedup vs baseline: 1.0240x; 1.0240x over previous
//
#include <hip/hip_runtime.h>
#include <math.h>

#define D_DIM    2048
#define BT_DIM   16384   // B*T
#define NSLOTS   4096
#define SCALE    0.02209708691207961f  // 1/sqrt(2048)
#define MARGIN   0.02f
#define CAND_MAX 16

typedef __attribute__((ext_vector_type(8))) short bf16x8;
typedef __attribute__((ext_vector_type(4))) float f32x4;
typedef __attribute__((ext_vector_type(8))) unsigned short u16x8;
typedef __attribute__((ext_vector_type(4))) unsigned short u16x4;

__device__ __forceinline__ unsigned short f2bf(float f) {
    unsigned int u = __float_as_uint(f);
    return (unsigned short)((u + 0x7fffu + ((u >> 16) & 1u)) >> 16);
}
__device__ __forceinline__ float bf2f(unsigned short s) {
    return __uint_as_float(((unsigned int)s) << 16);
}

__device__ __forceinline__ void async_cp16(const void* g, void* l) {
    __builtin_amdgcn_global_load_lds(
        (const __attribute__((address_space(1))) void*)g,
        (__attribute__((address_space(3))) void*)l, 16, 0, 0);
}

// ---------------------------------------------------------------------------
// top-4 helpers (jax semantics: val desc, idx asc) -- used in exact re-score
// ---------------------------------------------------------------------------
__device__ __forceinline__ bool cand_better(float v, int i, float v2, int i2) {
    return (v > v2) || (v == v2 && i < i2);
}

__device__ __forceinline__ void cand_insert(float v, int idx,
                                            float& v0, int& i0, float& v1, int& i1,
                                            float& v2, int& i2, float& v3, int& i3) {
    if (cand_better(v, idx, v3, i3)) {
        if (cand_better(v, idx, v0, i0)) {
            v3 = v2; i3 = i2; v2 = v1; i2 = i1; v1 = v0; i1 = i0; v0 = v; i0 = idx;
        } else if (cand_better(v, idx, v1, i1)) {
            v3 = v2; i3 = i2; v2 = v1; i2 = i1; v1 = v; i1 = idx;
        } else if (cand_better(v, idx, v2, i2)) {
            v3 = v2; i3 = i2; v2 = v; i2 = idx;
        } else {
            v3 = v; i3 = idx;
        }
    }
}

// ---------------------------------------------------------------------------
// 3-way bf16 split: v = h + m + l (each bf16, residual ~2^-27 |v|)
// r15 lesson: the f16 2-product alternative costs MORE (2 persistent
// accumulators -> occupancy loss beats halved MFMA count). Keep bf16x3.
// ---------------------------------------------------------------------------
__device__ __forceinline__ void split3v(float v, unsigned short& h,
                                        unsigned short& m, unsigned short& l) {
    h = f2bf(v);
    const float r1 = v - bf2f(h);
    m = f2bf(r1);
    l = f2bf(r1 - bf2f(m));
}

// SK -> 3 bf16 component arrays (linear, 4 elems/thread)
__global__ __launch_bounds__(256)
void split3_lin(const float* __restrict__ in, unsigned short* __restrict__ oh,
                unsigned short* __restrict__ om, unsigned short* __restrict__ ol) {
    const size_t i = ((size_t)blockIdx.x * 256 + threadIdx.x) * 4;
    const float4 v = *(const float4*)(in + i);
    u16x4 h, m, l;
    unsigned short th, tm, tl;
    split3v(v.x, th, tm, tl); h[0] = th; m[0] = tm; l[0] = tl;
    split3v(v.y, th, tm, tl); h[1] = th; m[1] = tm; l[1] = tl;
    split3v(v.z, th, tm, tl); h[2] = th; m[2] = tm; l[2] = tl;
    split3v(v.w, th, tm, tl); h[3] = th; m[3] = tm; l[3] = tl;
    *(u16x4*)(oh + i) = h;
    *(u16x4*)(om + i) = m;
    *(u16x4*)(ol + i) = l;
}

// Wq[e][d] -> transposed 3 bf16 component arrays out[d][e]  (32x32 LDS tiles)
__global__ __launch_bounds__(256)
void split3_wqT(const float* __restrict__ W, unsigned short* __restrict__ th,
                unsigned short* __restrict__ tm, unsigned short* __restrict__ tl) {
    __shared__ float tile[32][33];
    const int tx  = threadIdx.x & 31;
    const int ty4 = (threadIdx.x >> 5) * 4;
    const int e0  = blockIdx.y * 32;
    const int d0  = blockIdx.x * 32;
#pragma unroll
    for (int r = 0; r < 4; ++r)
        tile[ty4 + r][tx] = W[(size_t)(e0 + ty4 + r) * D_DIM + (d0 + tx)];
    __syncthreads();
#pragma unroll
    for (int r = 0; r < 4; ++r) {
        const float v = tile[tx][ty4 + r];   // = W[e0+tx][d0+ty4+r]
        unsigned short h, m, l;
        split3v(v, h, m, l);
        const size_t o = (size_t)(d0 + ty4 + r) * D_DIM + (e0 + tx);
        th[o] = h; tm[o] = m; tl[o] = l;
    }
}

// ---------------------------------------------------------------------------
// r16: single fused fp32->bf16 conversion over three tensors (x, wout, sv).
// Grid-stride over concatenated 8-elem chunk ranges; saves 2 launches.
// ---------------------------------------------------------------------------
__global__ __launch_bounds__(256)
void cvt3_f32_bf16(const float* __restrict__ a, unsigned short* __restrict__ oa, long na,
                   const float* __restrict__ b, unsigned short* __restrict__ ob, long nb,
                   const float* __restrict__ c, unsigned short* __restrict__ oc, long nc) {
    const long tot = na + nb + nc;
    const long stride = (long)gridDim.x * 256;
    for (long id = (long)blockIdx.x * 256 + threadIdx.x; id < tot; id += stride) {
        const float* src;
        unsigned short* dst;
        long off;
        if (id < na)           { src = a; dst = oa; off = id; }
        else if (id < na + nb) { src = b; dst = ob; off = id - na; }
        else                   { src = c; dst = oc; off = id - na - nb; }
        const size_t i = (size_t)off * 8;
        float4 v0 = *(const float4*)(src + i);
        float4 v1 = *(const float4*)(src + i + 4);
        u16x8 o;
        o[0] = f2bf(v0.x); o[1] = f2bf(v0.y); o[2] = f2bf(v0.z); o[3] = f2bf(v0.w);
        o[4] = f2bf(v1.x); o[5] = f2bf(v1.y); o[6] = f2bf(v1.z); o[7] = f2bf(v1.w);
        *(u16x8*)(dst + i) = o;
    }
}

// ---------------------------------------------------------------------------
// KW = SK @ Wq via 6-product split-bf16 MFMA (fp32-grade) -- r12 validated.
// ---------------------------------------------------------------------------
__global__ __launch_bounds__(256)
void gemm_kw_mfma6(const unsigned short* __restrict__ Ah,
                   const unsigned short* __restrict__ Am,
                   const unsigned short* __restrict__ Al,
                   const unsigned short* __restrict__ Bh,
                   const unsigned short* __restrict__ Bm,
                   const unsigned short* __restrict__ Bl,
                   float* __restrict__ KW, unsigned short* __restrict__ kwb,
                   int M, int N, int K) {
    __shared__ __align__(16) unsigned short AldsH[128 * 32];
    __shared__ __align__(16) unsigned short AldsM[128 * 32];
    __shared__ __align__(16) unsigned short AldsL[128 * 32];
    __shared__ __align__(16) unsigned short BldsH[128 * 32];
    __shared__ __align__(16) unsigned short BldsM[128 * 32];
    __shared__ __align__(16) unsigned short BldsL[128 * 32];

    const int tid  = threadIdx.x;
    const int lane = tid & 63;
    const int w    = tid >> 6;
    const int wr   = w >> 1, wc = w & 1;
    const int bmr  = blockIdx.y * 128;
    const int bnc  = blockIdx.x * 128;

    const int srow = lane >> 2;
    const int skch = (lane & 3) ^ ((lane >> 3) & 3);
    const int c0 = w, c1 = w + 4;
    size_t oA0 = (size_t)(bmr + c0 * 16 + srow) * K + skch * 8;
    size_t oA1 = (size_t)(bmr + c1 * 16 + srow) * K + skch * 8;
    size_t oB0 = (size_t)(bnc + c0 * 16 + srow) * K + skch * 8;
    size_t oB1 = (size_t)(bnc + c1 * 16 + srow) * K + skch * 8;
    char* lAh0 = (char*)AldsH + c0 * 1024;  char* lAh1 = (char*)AldsH + c1 * 1024;
    char* lAm0 = (char*)AldsM + c0 * 1024;  char* lAm1 = (char*)AldsM + c1 * 1024;
    char* lAl0 = (char*)AldsL + c0 * 1024;  char* lAl1 = (char*)AldsL + c1 * 1024;
    char* lBh0 = (char*)BldsH + c0 * 1024;  char* lBh1 = (char*)BldsH + c1 * 1024;
    char* lBm0 = (char*)BldsM + c0 * 1024;  char* lBm1 = (char*)BldsM + c1 * 1024;
    char* lBl0 = (char*)BldsL + c0 * 1024;  char* lBl1 = (char*)BldsL + c1 * 1024;

    const int kbyte = (((lane >> 4) ^ ((lane >> 1) & 3)) << 4);
    const int rA = wr * 64 + (lane & 15);
    const int rB = wc * 64 + (lane & 15);

    f32x4 acc[4][4] = {};

    for (int kt = 0; kt < K; kt += 32) {
        async_cp16(Ah + oA0, lAh0);  async_cp16(Ah + oA1, lAh1);
        async_cp16(Am + oA0, lAm0);  async_cp16(Am + oA1, lAm1);
        async_cp16(Al + oA0, lAl0);  async_cp16(Al + oA1, lAl1);
        async_cp16(Bh + oB0, lBh0);  async_cp16(Bh + oB1, lBh1);
        async_cp16(Bm + oB0, lBm0);  async_cp16(Bm + oB1, lBm1);
        async_cp16(Bl + oB0, lBl0);  async_cp16(Bl + oB1, lBl1);
        oA0 += 32; oA1 += 32; oB0 += 32; oB1 += 32;
        __syncthreads();

        bf16x8 afh[4], afm[4], afl[4], bfh[4], bfm[4], bfl[4];
#pragma unroll
        for (int i = 0; i < 4; ++i) {
            const int ar = (rA + i * 16) * 64 + kbyte;
            afh[i] = *(const bf16x8*)((const char*)AldsH + ar);
            afm[i] = *(const bf16x8*)((const char*)AldsM + ar);
            afl[i] = *(const bf16x8*)((const char*)AldsL + ar);
            const int br = (rB + i * 16) * 64 + kbyte;
            bfh[i] = *(const bf16x8*)((const char*)BldsH + br);
            bfm[i] = *(const bf16x8*)((const char*)BldsM + br);
            bfl[i] = *(const bf16x8*)((const char*)BldsL + br);
        }
#pragma unroll
        for (int i = 0; i < 4; ++i)
#pragma unroll
            for (int j = 0; j < 4; ++j) {
                f32x4 c = acc[i][j];
                c = __builtin_amdgcn_mfma_f32_16x16x32_bf16(afh[i], bfh[j], c, 0, 0, 0);
                c = __builtin_amdgcn_mfma_f32_16x16x32_bf16(afh[i], bfm[j], c, 0, 0, 0);
                c = __builtin_amdgcn_mfma_f32_16x16x32_bf16(afm[i], bfh[j], c, 0, 0, 0);
                c = __builtin_amdgcn_mfma_f32_16x16x32_bf16(afm[i], bfm[j], c, 0, 0, 0);
                c = __builtin_amdgcn_mfma_f32_16x16x32_bf16(afh[i], bfl[j], c, 0, 0, 0);
                c = __builtin_amdgcn_mfma_f32_16x16x32_bf16(afl[i], bfh[j], c, 0, 0, 0);
                acc[i][j] = c;
            }
        __syncthreads();
    }

    const int orow = (lane >> 4) * 4;
    const int ocol = lane & 15;
#pragma unroll
    for (int i = 0; i < 4; ++i)
#pragma unroll
        for (int j = 0; j < 4; ++j) {
            const size_t base =
                (size_t)(bmr + wr * 64 + i * 16 + orow) * N + (bnc + wc * 64 + j * 16 + ocol);
#pragma unroll
            for (int r = 0; r < 4; ++r) {
                const float v = acc[i][j][r];
                KW[base + (size_t)r * N]  = v;
                kwb[base + (size_t)r * N] = f2bf(v);
            }
        }
}

// ---------------------------------------------------------------------------
// bf16 MFMA GEMM: C[M,N] = A[M,K] @ B[N,K]^T; C fp32 or bf16 (template).
// r7 exact baseline (no swizzle, no epilogue fusion -- r8/r10 lessons).
// Used for: scores (bf16 out), SVW = SV @ Wout^T (fp32 out).
// ---------------------------------------------------------------------------
template <bool BF16_OUT>
__global__ __launch_bounds__(256)
void gemm_bf16_abt(const unsigned short* __restrict__ A,
                   const unsigned short* __restrict__ B,
                   void* __restrict__ Cv, int M, int N, int K) {
    __shared__ __align__(16) unsigned short Alds[128 * 32];
    __shared__ __align__(16) unsigned short Blds[128 * 32];

    const int tid  = threadIdx.x;
    const int lane = tid & 63;
    const int w    = tid >> 6;
    const int wr   = w >> 1, wc = w & 1;
    const int bm   = blockIdx.y * 128;
    const int bn   = blockIdx.x * 128;

    const int srow = lane >> 2;
    const int skch = (lane & 3) ^ ((lane >> 3) & 3);
    const int c0 = w, c1 = w + 4;
    const unsigned short* gA0 = A + (size_t)(bm + c0 * 16 + srow) * K + skch * 8;
    const unsigned short* gA1 = A + (size_t)(bm + c1 * 16 + srow) * K + skch * 8;
    const unsigned short* gB0 = B + (size_t)(bn + c0 * 16 + srow) * K + skch * 8;
    const unsigned short* gB1 = B + (size_t)(bn + c1 * 16 + srow) * K + skch * 8;
    char* lA0 = (char*)Alds + c0 * 1024;
    char* lA1 = (char*)Alds + c1 * 1024;
    char* lB0 = (char*)Blds + c0 * 1024;
    char* lB1 = (char*)Blds + c1 * 1024;

    const int kbyte = (((lane >> 4) ^ ((lane >> 1) & 3)) << 4);
    const int rA = wr * 64 + (lane & 15);
    const int rB = wc * 64 + (lane & 15);

    f32x4 acc[4][4] = {};

    for (int kt = 0; kt < K; kt += 32) {
        async_cp16(gA0, lA0);
        async_cp16(gA1, lA1);
        async_cp16(gB0, lB0);
        async_cp16(gB1, lB1);
        gA0 += 32; gA1 += 32; gB0 += 32; gB1 += 32;
        __syncthreads();

        bf16x8 a[4], b[4];
#pragma unroll
        for (int i = 0; i < 4; ++i) {
            a[i] = *(const bf16x8*)((const char*)Alds + (rA + i * 16) * 64 + kbyte);
            b[i] = *(const bf16x8*)((const char*)Blds + (rB + i * 16) * 64 + kbyte);
        }
#pragma unroll
        for (int i = 0; i < 4; ++i)
#pragma unroll
            for (int j = 0; j < 4; ++j)
                acc[i][j] = __builtin_amdgcn_mfma_f32_16x16x32_bf16(
                    a[i], b[j], acc[i][j], 0, 0, 0);
        __syncthreads();
    }

    const int orow = (lane >> 4) * 4;
    const int ocol = lane & 15;
#pragma unroll
    for (int i = 0; i < 4; ++i)
#pragma unroll
        for (int j = 0; j < 4; ++j) {
            const size_t base =
                (size_t)(bm + wr * 64 + i * 16 + orow) * N + (bn + wc * 64 + j * 16 + ocol);
#pragma unroll
            for (int r = 0; r < 4; ++r) {
                if constexpr (BF16_OUT)
                    ((unsigned short*)Cv)[base + (size_t)r * N] = f2bf(acc[i][j][r]);
                else
                    ((float*)Cv)[base + (size_t)r * N] = acc[i][j][r];
            }
        }
}

// ---------------------------------------------------------------------------
// Merged refine (r13 validated) + SVW-gather epilogue (r14 validated):
//   branchless in-register row top-4 -> margin candidates -> EXACT fp32
//   re-score (identical math, rounds 2-14) -> softmax ->
//   out_row = sum_k attn_k * SVW[idx_k]   (fp32 gather, writes d_out direct)
// ---------------------------------------------------------------------------
__global__ __launch_bounds__(256)
void topk_refine(const unsigned short* __restrict__ scoresb,
                 const float* __restrict__ x,
                 const float* __restrict__ KW,
                 const float* __restrict__ SVW,
                 float* __restrict__ out) {
    const int tid  = threadIdx.x;
    const int lane = tid & 63;
    const int w    = tid >> 6;
    const int t    = blockIdx.x * 4 + w;
    const unsigned short* srow = scoresb + (size_t)t * NSLOTS;

    __shared__ int cand[4][CAND_MAX];
    __shared__ int ncand[4];

    // ---- load 64 bf16 scores/lane, build order-isomorphic packed keys
    unsigned int k[64];
#pragma unroll
    for (int j = 0; j < 8; ++j) {
        const int c0 = j * 512 + lane * 8;
        const u16x8 s8 = *(const u16x8*)(srow + c0);
#pragma unroll
        for (int e = 0; e < 8; ++e) {
            const unsigned int b   = (unsigned int)s8[e] & 0xffffu;
            const unsigned int ord = b ^ ((b & 0x8000u) ? 0xffffu : 0x8000u);
            k[j * 8 + e] = (ord << 12) | (4095u - (unsigned int)(c0 + e));
        }
    }

    // ---- branchless top-4 over the whole row
    unsigned int win[4];
#pragma unroll
    for (int p = 0; p < 4; ++p) {
        unsigned int a16[16];
#pragma unroll
        for (int e = 0; e < 16; ++e)
            a16[e] = max(max(k[e], k[e + 16]), max(k[e + 32], k[e + 48]));
        unsigned int a4[4];
#pragma unroll
        for (int e = 0; e < 4; ++e)
            a4[e] = max(max(a16[e], a16[e + 4]), max(a16[e + 8], a16[e + 12]));
        unsigned int m = max(max(a4[0], a4[1]), max(a4[2], a4[3]));
#pragma unroll
        for (int off = 1; off < 64; off <<= 1)
            m = max(m, (unsigned int)__shfl_xor((int)m, off));
        win[p] = m;
#pragma unroll
        for (int e = 0; e < 64; ++e) k[e] = (k[e] == m) ? 0u : k[e];
    }

    // decode 4th-best value -> threshold
    const unsigned int ord3 = win[3] >> 12;
    const unsigned int b3 =
        (ord3 & 0x8000u) ? (ord3 ^ 0x8000u) : (~ord3 & 0xffffu);
    const float thresh = bf2f((unsigned short)b3) - MARGIN;

    if (lane == 0) {
        ncand[w] = 4;
        cand[w][0] = 4095 - (int)(win[0] & 0xfffu);
        cand[w][1] = 4095 - (int)(win[1] & 0xfffu);
        cand[w][2] = 4095 - (int)(win[2] & 0xfffu);
        cand[w][3] = 4095 - (int)(win[3] & 0xfffu);
    }
    __syncthreads();

    // ---- margin candidates from remaining keys (masked keys decode NaN)
#pragma unroll
    for (int e = 0; e < 64; ++e) {
        const unsigned int kk  = k[e];
        const unsigned int ordv = kk >> 12;
        const unsigned int bv =
            (ordv & 0x8000u) ? (ordv ^ 0x8000u) : (~ordv & 0xffffu);
        if (bf2f((unsigned short)bv) >= thresh) {
            int p = atomicAdd(&ncand[w], 1);
            if (p < CAND_MAX) cand[w][p] = 4095 - (int)(kk & 0xfffu);
        }
    }
    __syncthreads();
    const int nc = min(ncand[w], CAND_MAX);

    // ---- exact fp32 re-score (IDENTICAL math to rounds 2-14 validated path)
    const float* xrow = x + (size_t)t * D_DIM + lane * 4;
    float4 xv[8];
#pragma unroll
    for (int i = 0; i < 8; ++i) xv[i] = *(const float4*)(xrow + 256 * i);

    float r0 = -INFINITY, r1 = -INFINITY, r2 = -INFINITY, r3 = -INFINITY;
    int   q0 = 0x7fffffff, q1 = 0x7fffffff, q2 = 0x7fffffff, q3 = 0x7fffffff;
    for (int c = 0; c < nc; ++c) {
        const int slot = cand[w][c];
        const float* kr = KW + (size_t)slot * D_DIM + lane * 4;
        float p = 0.0f;
#pragma unroll
        for (int i = 0; i < 8; ++i) {
            const float4 k4 = *(const float4*)(kr + 256 * i);
            p = fmaf(xv[i].x, k4.x, p);
            p = fmaf(xv[i].y, k4.y, p);
            p = fmaf(xv[i].z, k4.z, p);
            p = fmaf(xv[i].w, k4.w, p);
        }
#pragma unroll
        for (int off = 1; off < 64; off <<= 1) p += __shfl_xor(p, off);
        cand_insert(p, slot, r0, q0, r1, q1, r2, q2, r3, q3);
    }

    // ---- softmax over scaled top-4 (r0 is max)
    const float e1s = expf(SCALE * (r1 - r0));
    const float e2s = expf(SCALE * (r2 - r0));
    const float e3s = expf(SCALE * (r3 - r0));
    const float inv = 1.0f / (1.0f + e1s + e2s + e3s);
    const float w0s = inv, w1s = e1s * inv, w2s = e2s * inv, w3s = e3s * inv;

    // ---- gather fp32 SVW rows, weighted sum, write d_out directly
    const float* p0 = SVW + (size_t)q0 * D_DIM;
    const float* p1 = SVW + (size_t)q1 * D_DIM;
    const float* p2 = SVW + (size_t)q2 * D_DIM;
    const float* p3 = SVW + (size_t)q3 * D_DIM;
    float* orow = out + (size_t)t * D_DIM;
#pragma unroll
    for (int i = 0; i < 4; ++i) {
        const int d0 = lane * 8 + 512 * i;
        float4 a0 = *(const float4*)(p0 + d0), b0 = *(const float4*)(p0 + d0 + 4);
        float4 a1 = *(const float4*)(p1 + d0), b1 = *(const float4*)(p1 + d0 + 4);
        float4 a2 = *(const float4*)(p2 + d0), b2 = *(const float4*)(p2 + d0 + 4);
        float4 a3 = *(const float4*)(p3 + d0), b3v = *(const float4*)(p3 + d0 + 4);
        float4 oa, ob;
        oa.x = w0s * a0.x + w1s * a1.x + w2s * a2.x + w3s * a3.x;
        oa.y = w0s * a0.y + w1s * a1.y + w2s * a2.y + w3s * a3.y;
        oa.z = w0s * a0.z + w1s * a1.z + w2s * a2.z + w3s * a3.z;
        oa.w = w0s * a0.w + w1s * a1.w + w2s * a2.w + w3s * a3.w;
        ob.x = w0s * b0.x + w1s * b1.x + w2s * b2.x + w3s * b3v.x;
        ob.y = w0s * b0.y + w1s * b1.y + w2s * b2.y + w3s * b3v.y;
        ob.z = w0s * b0.z + w1s * b1.z + w2s * b2.z + w3s * b3v.z;
        ob.w = w0s * b0.w + w1s * b1.w + w2s * b2.w + w3s * b3v.w;
        *(float4*)(orow + d0)     = oa;
        *(float4*)(orow + d0 + 4) = ob;
    }
}

// ---------------------------------------------------------------------------
extern "C" void kernel_launch(void* const* d_in, const int* in_sizes, int n_in,
                              void* d_out, int out_size, void* d_ws, size_t ws_size,
                              hipStream_t stream) {
    const float* x    = (const float*)d_in[0];
    const float* sk   = (const float*)d_in[1];
    const float* sv   = (const float*)d_in[2];
    const float* wq   = (const float*)d_in[3];
    const float* wout = (const float*)d_in[4];

    // workspace layout (r1 proved ws >= 402.6 MB)
    char* base = (char*)d_ws;
    unsigned short* scoresb = (unsigned short*)base;              // 134.2 MB
    float*          KW      = (float*)(base + 134217728);         //  33.55 MB
    unsigned short* kwb     = (unsigned short*)(base + 167772160);//  16.78 MB
    unsigned short* woutb   = (unsigned short*)(base + 184549376);//   8.39 MB
    unsigned short* xb      = (unsigned short*)(base + 192937984);//  67.11 MB
    unsigned short* svb     = (unsigned short*)(base + 260046848);//  16.78 MB
    unsigned short* skh     = (unsigned short*)(base + 293601280);//  16.78 MB (dead after kw)
    unsigned short* skm     = (unsigned short*)(base + 310378496);//  16.78 MB (dead after kw)
    unsigned short* skl     = (unsigned short*)(base + 327155712);//  16.78 MB (dead after kw)
    unsigned short* wqth    = (unsigned short*)(base + 343932928);//   8.39 MB
    unsigned short* wqtm    = (unsigned short*)(base + 352321536);//   8.39 MB
    unsigned short* wqtl    = (unsigned short*)(base + 360710144);//   8.39 MB
    float*          SVW     = (float*)(base + 293601280);         //  33.55 MB (over skh/skm)

    const dim3 blk(256);

    // 3-way bf16 splits: SK (linear) and Wq (transposed)
    split3_lin<<<dim3((NSLOTS * (size_t)D_DIM) / 1024), blk, 0, stream>>>(
        sk, skh, skm, skl);
    split3_wqT<<<dim3(D_DIM / 32, D_DIM / 32), blk, 0, stream>>>(
        wq, wqth, wqtm, wqtl);

    // fused bf16 conversions: x, wout, sv in one launch (r16)
    cvt3_f32_bf16<<<dim3(2048), blk, 0, stream>>>(
        x,    xb,    (long)(BT_DIM * (size_t)D_DIM / 8),
        wout, woutb, (long)(D_DIM * (size_t)D_DIM / 8),
        sv,   svb,   (long)(NSLOTS * (size_t)D_DIM / 8));

    // KW (fp32) + kwb (bf16) via 6-product split-bf16 MFMA (r12 validated)
    gemm_kw_mfma6<<<dim3(D_DIM / 128, NSLOTS / 128), blk, 0, stream>>>(
        skh, skm, skl, wqth, wqtm, wqtl, KW, kwb, NSLOTS, D_DIM, D_DIM);

    // SVW = SV @ Wout^T (fp32 out) -- launched AFTER kw (overwrites skh/skm)
    gemm_bf16_abt<false><<<dim3(D_DIM / 128, NSLOTS / 128), blk, 0, stream>>>(
        svb, woutb, SVW, NSLOTS, D_DIM, D_DIM);

    // approx scores (bf16 out) = xb @ kwb^T
    gemm_bf16_abt<true><<<dim3(NSLOTS / 128, BT_DIM / 128), blk, 0, stream>>>(
        xb, kwb, scoresb, BT_DIM, NSLOTS, D_DIM);

    // merged top-4 + exact refine + SVW gather -> writes d_out directly
    topk_refine<<<dim3(BT_DIM / 4), blk, 0, stream>>>(
        scoresb, x, KW, SVW, (float*)d_out);
}